// Round 9
// baseline (417.665 us; speedup 1.0000x reference)
//
#include <hip/hip_runtime.h>

// ---------------------------------------------------------------------------
// 3-layer GCN (DGL GraphConv norm='both') on MI355X.
// Round 9: (a) gathers widened to dwordx2/lane (2 edges per wave-load,
// halves VMEM+addr instruction count; shfl_xor edge-slot reduction);
// (b) GEMM epilogues store in register-native permuted feature order
// (phi = l15*NT + t) -> 4-8 coalesced wide stores/wave instead of 64
// scalar 2B stores; W2/W3 K-dims pre-permuted to match; gather64
// un-permutes in its fp32 epilogue (stays coalesced).
// ---------------------------------------------------------------------------

typedef float f32x4 __attribute__((ext_vector_type(4)));
typedef __bf16 bf16x8 __attribute__((ext_vector_type(8)));

constexpr int CAP = 5120;    // bucket capacity; mean fill 4092
constexpr int MAXNB = 400;   // max buckets (256 nodes each; N <= 102400)

__device__ inline unsigned short f2bf_bits(float f) {  // RNE
    unsigned u = __float_as_uint(f);
    unsigned r = u + 0x7fff + ((u >> 16) & 1);
    return (unsigned short)(r >> 16);
}
__device__ inline float bf_bits2f(unsigned short s) {
    return __uint_as_float(((unsigned)s) << 16);
}
__device__ inline float bf_lo(unsigned v) { return __uint_as_float(v << 16); }
__device__ inline float bf_hi(unsigned v) { return __uint_as_float(v & 0xffff0000u); }
__device__ inline unsigned pack_bf2(float x0, float x1) {
    return ((unsigned)f2bf_bits(x1) << 16) | (unsigned)f2bf_bits(x0);
}

// ---------------- bucketed CSR build (unchanged from r8) ----------------

__global__ __launch_bounds__(512) void bucket_scatter(
    const int* __restrict__ src, const int* __restrict__ dst,
    int* __restrict__ cur_d, int* __restrict__ cur_s,
    int* __restrict__ bpair, int* __restrict__ bsrc, int E, int NB) {
    __shared__ int hd[MAXNB], hs[MAXNB], bd[MAXNB], bs[MAXNB];
    const int tid = threadIdx.x;
    for (int i = tid; i < NB; i += 512) { hd[i] = 0; hs[i] = 0; }
    __syncthreads();

    const int base = (blockIdx.x * 512 + tid) * 8;
    int s[8], d[8], rd[8], rs[8];
    bool va[8];
    if (base + 8 <= E) {
        const int4 s0 = *(const int4*)(src + base);
        const int4 s1 = *(const int4*)(src + base + 4);
        const int4 d0 = *(const int4*)(dst + base);
        const int4 d1 = *(const int4*)(dst + base + 4);
        s[0] = s0.x; s[1] = s0.y; s[2] = s0.z; s[3] = s0.w;
        s[4] = s1.x; s[5] = s1.y; s[6] = s1.z; s[7] = s1.w;
        d[0] = d0.x; d[1] = d0.y; d[2] = d0.z; d[3] = d0.w;
        d[4] = d1.x; d[5] = d1.y; d[6] = d1.z; d[7] = d1.w;
#pragma unroll
        for (int j = 0; j < 8; ++j) va[j] = true;
    } else {
#pragma unroll
        for (int j = 0; j < 8; ++j) {
            const int e = base + j;
            va[j] = e < E;
            const int ec = va[j] ? e : 0;
            s[j] = src[ec];
            d[j] = dst[ec];
        }
    }
#pragma unroll
    for (int j = 0; j < 8; ++j) {
        if (va[j]) {
            rd[j] = atomicAdd(&hd[d[j] >> 8], 1);
            rs[j] = atomicAdd(&hs[s[j] >> 8], 1);
        }
    }
    __syncthreads();
    for (int i = tid; i < NB; i += 512) {
        bd[i] = hd[i] ? atomicAdd(&cur_d[i], hd[i]) : 0;
        bs[i] = hs[i] ? atomicAdd(&cur_s[i], hs[i]) : 0;
    }
    __syncthreads();
#pragma unroll
    for (int j = 0; j < 8; ++j) {
        if (va[j]) {
            const int b = d[j] >> 8;
            const int pos = bd[b] + rd[j];
            if (pos < CAP) bpair[(size_t)b * CAP + pos] = (s[j] << 8) | (d[j] & 255);
            const int c = s[j] >> 8;
            const int ps = bs[c] + rs[j];
            if (ps < CAP) bsrc[(size_t)c * CAP + ps] = s[j];
        }
    }
}

__global__ __launch_bounds__(512) void bucket_scan(
    const int* __restrict__ cur_d, int* __restrict__ bbase, int NB) {
    __shared__ int s[512];
    const int tid = threadIdx.x;
    s[tid] = (tid < NB) ? cur_d[tid] : 0;
    __syncthreads();
    for (int off = 1; off < 512; off <<= 1) {
        int v = (tid >= off) ? s[tid - off] : 0;
        __syncthreads();
        s[tid] += v;
        __syncthreads();
    }
    if (tid < NB) bbase[tid] = (tid > 0) ? s[tid - 1] : 0;
}

__global__ __launch_bounds__(256) void csr_outdeg(
    const int* __restrict__ bpair, const int* __restrict__ bsrc,
    const int* __restrict__ bcnt_d, const int* __restrict__ bcnt_s,
    const int* __restrict__ bbase, int* __restrict__ row_ptr,
    int* __restrict__ col, float* __restrict__ isi, float* __restrict__ iso,
    float* __restrict__ fscale, int N, int NB) {
    __shared__ int h[256], hs[256], sc[256], cur[256];
    const int b = blockIdx.x;
    const int tid = threadIdx.x;
    const int cnt = min(bcnt_d[b], CAP);
    const int scnt = min(bcnt_s[b], CAP);
    const int base = bbase[b];
    const int* pairs = bpair + (size_t)b * CAP;
    const int* svals = bsrc + (size_t)b * CAP;
    h[tid] = 0;
    hs[tid] = 0;
    __syncthreads();
    for (int i = tid; i < cnt; i += 256) atomicAdd(&h[pairs[i] & 255], 1);
    for (int i = tid; i < scnt; i += 256) atomicAdd(&hs[svals[i] & 255], 1);
    __syncthreads();
    sc[tid] = h[tid];
    __syncthreads();
    for (int off = 1; off < 256; off <<= 1) {
        int v = (tid >= off) ? sc[tid - off] : 0;
        __syncthreads();
        sc[tid] += v;
        __syncthreads();
    }
    const int lp = sc[tid] - h[tid];
    const int node = b * 256 + tid;
    if (node < N) {
        row_ptr[node] = base + lp;
        const float di = (h[tid] > 0) ? rsqrtf((float)h[tid]) : 0.f;
        const float dw = (hs[tid] > 0) ? rsqrtf((float)hs[tid]) : 0.f;
        isi[node] = di;
        iso[node] = dw;
        fscale[node] = di * dw;
    }
    if (b == NB - 1 && tid == 0) row_ptr[N] = base + cnt;
    cur[tid] = lp;
    __syncthreads();
    for (int i = tid; i < cnt; i += 256) {
        const int p = pairs[i];
        const int pos = base + atomicAdd(&cur[p & 255], 1);
        col[pos] = p >> 8;
    }
}

// ---------------- W pre-pack ----------------
// W1: true K order (layer-1 A is fp32 features).
// W2/W3: K permuted by phi1 (gemm NT=8 output order): k = ((phi&7)<<4)|(phi>>3).

__device__ inline void wpack_true(const float* W, unsigned short* Wh,
                                  unsigned short* Wl, int t, int F) {
    const int n = t >> 7, k = t & 127;
    const float w = W[k * F + n];
    const unsigned short hb = f2bf_bits(w);
    Wh[t] = hb;
    Wl[t] = f2bf_bits(w - bf_bits2f(hb));
}

__device__ inline void wpack_perm(const float* W, unsigned short* Wh,
                                  unsigned short* Wl, int t, int F) {
    const int n = t >> 7, phi = t & 127;
    const int k = ((phi & 7) << 4) | (phi >> 3);
    const float w = W[k * F + n];
    const unsigned short hb = f2bf_bits(w);
    Wh[t] = hb;
    Wl[t] = f2bf_bits(w - bf_bits2f(hb));
}

__global__ __launch_bounds__(256) void wpack_all(
    const float* __restrict__ W1, const float* __restrict__ W2,
    const float* __restrict__ W3, unsigned short* __restrict__ Wt1h,
    unsigned short* __restrict__ Wt1l, unsigned short* __restrict__ Wt2h,
    unsigned short* __restrict__ Wt2l, unsigned short* __restrict__ Wt3h,
    unsigned short* __restrict__ Wt3l) {
    int t = blockIdx.x * 256 + threadIdx.x;
    if (t < 16384) {
        wpack_true(W1, Wt1h, Wt1l, t, 128);
    } else if (t < 32768) {
        wpack_perm(W2, Wt2h, Wt2l, t - 16384, 128);
    } else if (t < 40960) {
        wpack_perm(W3, Wt3h, Wt3l, t - 32768, 64);
    }
}

// ---------------- permuted epilogue helper ----------------
// Store lane's NT accumulator elems (row r) as NT/2 packed dwords at
// ushort offset node*F + l15*NT  (phi = l15*NT + t).

template <int NT>
__device__ inline void store_row_perm(unsigned short* __restrict__ Y,
                                      const f32x4* acc, int r, size_t node,
                                      int l15) {
    unsigned pk[NT / 2];
#pragma unroll
    for (int t = 0; t < NT; t += 2) pk[t / 2] = pack_bf2(acc[t][r], acc[t + 1][r]);
    unsigned short* p = Y + node * (NT * 16) + l15 * NT;
    if constexpr (NT == 8) {
        *(uint4*)p = make_uint4(pk[0], pk[1], pk[2], pk[3]);
    } else {
        *(uint2*)p = make_uint2(pk[0], pk[1]);
    }
}

// ---------------- layer-1 GEMM: fp32 X (split A) x split W ----------------

template <int F>
__global__ __launch_bounds__(256) void gemm_mfma(
    const float* __restrict__ X, const unsigned short* __restrict__ Wt_hi,
    const unsigned short* __restrict__ Wt_lo, const float* __restrict__ so,
    unsigned short* __restrict__ Y, int N) {
    constexpr int NT = F / 16;
    const int wave = threadIdx.x >> 6;
    const int lane = threadIdx.x & 63;
    const int r0 = blockIdx.x * 128 + wave * 32;
    const int l15 = lane & 15;
    const int quad = lane >> 4;

    const int rowA0 = min(r0 + l15, N - 1);
    const int rowA1 = min(r0 + 16 + l15, N - 1);
    const float s0 = so[rowA0];
    const float s1 = so[rowA1];
    const float* pX0 = X + (size_t)rowA0 * 128 + quad * 8;
    const float* pX1 = X + (size_t)rowA1 * 128 + quad * 8;

    f32x4 acc0[NT], acc1[NT];
    const f32x4 z = {0.f, 0.f, 0.f, 0.f};
#pragma unroll
    for (int t = 0; t < NT; ++t) { acc0[t] = z; acc1[t] = z; }

    union AB { bf16x8 v; unsigned short u[8]; };

#pragma unroll
    for (int s = 0; s < 4; ++s) {
        const int kb = s * 32;
        AB bh[NT], bl[NT];
#pragma unroll
        for (int t = 0; t < NT; ++t) {
            const int n = t * 16 + l15;
            bh[t].v = *(const bf16x8*)(Wt_hi + n * 128 + kb + quad * 8);
            bl[t].v = *(const bf16x8*)(Wt_lo + n * 128 + kb + quad * 8);
        }
        float a[8];
        *(f32x4*)&a[0] = *(const f32x4*)(pX0 + kb);
        *(f32x4*)&a[4] = *(const f32x4*)(pX0 + kb + 4);
        AB ah, al;
#pragma unroll
        for (int j = 0; j < 8; ++j) {
            float x = a[j] * s0;
            unsigned short hb = f2bf_bits(x);
            ah.u[j] = hb;
            al.u[j] = f2bf_bits(x - bf_bits2f(hb));
        }
#pragma unroll
        for (int t = 0; t < NT; ++t) {
            acc0[t] = __builtin_amdgcn_mfma_f32_16x16x32_bf16(ah.v, bh[t].v, acc0[t], 0, 0, 0);
            acc0[t] = __builtin_amdgcn_mfma_f32_16x16x32_bf16(al.v, bh[t].v, acc0[t], 0, 0, 0);
            acc0[t] = __builtin_amdgcn_mfma_f32_16x16x32_bf16(ah.v, bl[t].v, acc0[t], 0, 0, 0);
        }
        *(f32x4*)&a[0] = *(const f32x4*)(pX1 + kb);
        *(f32x4*)&a[4] = *(const f32x4*)(pX1 + kb + 4);
#pragma unroll
        for (int j = 0; j < 8; ++j) {
            float x = a[j] * s1;
            unsigned short hb = f2bf_bits(x);
            ah.u[j] = hb;
            al.u[j] = f2bf_bits(x - bf_bits2f(hb));
        }
#pragma unroll
        for (int t = 0; t < NT; ++t) {
            acc1[t] = __builtin_amdgcn_mfma_f32_16x16x32_bf16(ah.v, bh[t].v, acc1[t], 0, 0, 0);
            acc1[t] = __builtin_amdgcn_mfma_f32_16x16x32_bf16(al.v, bh[t].v, acc1[t], 0, 0, 0);
            acc1[t] = __builtin_amdgcn_mfma_f32_16x16x32_bf16(ah.v, bl[t].v, acc1[t], 0, 0, 0);
        }
    }

#pragma unroll
    for (int r = 0; r < 4; ++r) {
        const int node0 = r0 + quad * 4 + r;
        if (node0 < N) store_row_perm<NT>(Y, acc0, r, (size_t)node0, l15);
        const int node1 = r0 + 16 + quad * 4 + r;
        if (node1 < N) store_row_perm<NT>(Y, acc1, r, (size_t)node1, l15);
    }
}

// ---------------- layers 2-3 GEMM: bf16 A (phi-permuted K) x perm W ----------

template <int F>
__global__ __launch_bounds__(256) void gemm_bf16A(
    const unsigned short* __restrict__ A, const unsigned short* __restrict__ Wt_hi,
    const unsigned short* __restrict__ Wt_lo, unsigned short* __restrict__ Y, int N) {
    constexpr int NT = F / 16;
    const int wave = threadIdx.x >> 6;
    const int lane = threadIdx.x & 63;
    const int r0 = blockIdx.x * 128 + wave * 32;
    const int l15 = lane & 15;
    const int quad = lane >> 4;

    const int rowA0 = min(r0 + l15, N - 1);
    const int rowA1 = min(r0 + 16 + l15, N - 1);
    const unsigned short* pA0 = A + (size_t)rowA0 * 128 + quad * 8;
    const unsigned short* pA1 = A + (size_t)rowA1 * 128 + quad * 8;

    f32x4 acc0[NT], acc1[NT];
    const f32x4 z = {0.f, 0.f, 0.f, 0.f};
#pragma unroll
    for (int t = 0; t < NT; ++t) { acc0[t] = z; acc1[t] = z; }

#pragma unroll
    for (int s = 0; s < 4; ++s) {
        const int kb = s * 32;
        bf16x8 bh[NT], bl[NT];
#pragma unroll
        for (int t = 0; t < NT; ++t) {
            const int n = t * 16 + l15;
            bh[t] = *(const bf16x8*)(Wt_hi + n * 128 + kb + quad * 8);
            bl[t] = *(const bf16x8*)(Wt_lo + n * 128 + kb + quad * 8);
        }
        const bf16x8 a0 = *(const bf16x8*)(pA0 + kb);
        const bf16x8 a1 = *(const bf16x8*)(pA1 + kb);
#pragma unroll
        for (int t = 0; t < NT; ++t) {
            acc0[t] = __builtin_amdgcn_mfma_f32_16x16x32_bf16(a0, bh[t], acc0[t], 0, 0, 0);
            acc0[t] = __builtin_amdgcn_mfma_f32_16x16x32_bf16(a0, bl[t], acc0[t], 0, 0, 0);
            acc1[t] = __builtin_amdgcn_mfma_f32_16x16x32_bf16(a1, bh[t], acc1[t], 0, 0, 0);
            acc1[t] = __builtin_amdgcn_mfma_f32_16x16x32_bf16(a1, bl[t], acc1[t], 0, 0, 0);
        }
    }

#pragma unroll
    for (int r = 0; r < 4; ++r) {
        const int node0 = r0 + quad * 4 + r;
        if (node0 < N) store_row_perm<NT>(Y, acc0, r, (size_t)node0, l15);
        const int node1 = r0 + 16 + quad * 4 + r;
        if (node1 < N) store_row_perm<NT>(Y, acc1, r, (size_t)node1, l15);
    }
}

// ---------------- Pull aggregation (dwordx2/lane, 2 edges per load) ----------

// Layers 1-2: writes bf16 A (permuted order preserved) with fscale + ReLU.
__global__ __launch_bounds__(256) void gather128_bf16(
    const unsigned short* __restrict__ msg, const int* __restrict__ row_ptr,
    const int* __restrict__ col, const float* __restrict__ fscale,
    unsigned short* __restrict__ outA, int N) {
    const int wave = (blockIdx.x * 256 + threadIdx.x) >> 6;
    const int lane = threadIdx.x & 63;
    if (wave >= N) return;
    const int es = lane >> 5;   // edge slot 0/1
    const int h = lane & 31;    // uint2 index within 256B row
    const int start = row_ptr[wave], end = row_ptr[wave + 1];
    const uint2* m64 = (const uint2*)msg;  // row stride 32 uint2

    float a0 = 0.f, a1 = 0.f, a2 = 0.f, a3 = 0.f;
    int e = start;
    const int efull = start + ((end - start) & ~7);
    for (; e < efull; e += 8) {
        int c[4];
        uint2 v[4];
#pragma unroll
        for (int jj = 0; jj < 4; ++jj) c[jj] = col[e + 2 * jj + es];
#pragma unroll
        for (int jj = 0; jj < 4; ++jj) v[jj] = m64[(size_t)c[jj] * 32 + h];
#pragma unroll
        for (int jj = 0; jj < 4; ++jj) {
            a0 += bf_lo(v[jj].x); a1 += bf_hi(v[jj].x);
            a2 += bf_lo(v[jj].y); a3 += bf_hi(v[jj].y);
        }
    }
    const int rem = end - e;
    if (rem > 0) {
        int c[4];
        uint2 v[4];
#pragma unroll
        for (int jj = 0; jj < 4; ++jj) c[jj] = col[e + min(2 * jj + es, rem - 1)];
#pragma unroll
        for (int jj = 0; jj < 4; ++jj) v[jj] = m64[(size_t)c[jj] * 32 + h];
#pragma unroll
        for (int jj = 0; jj < 4; ++jj) {
            if (2 * jj + es < rem) {
                a0 += bf_lo(v[jj].x); a1 += bf_hi(v[jj].x);
                a2 += bf_lo(v[jj].y); a3 += bf_hi(v[jj].y);
            }
        }
    }
    a0 += __shfl_xor(a0, 32); a1 += __shfl_xor(a1, 32);
    a2 += __shfl_xor(a2, 32); a3 += __shfl_xor(a3, 32);
    if (es == 0) {
        const float sc = fscale[wave];
        a0 = fmaxf(a0 * sc, 0.f); a1 = fmaxf(a1 * sc, 0.f);
        a2 = fmaxf(a2 * sc, 0.f); a3 = fmaxf(a3 * sc, 0.f);
        uint2 p = make_uint2(pack_bf2(a0, a1), pack_bf2(a2, a3));
        *(uint2*)(outA + (size_t)wave * 128 + h * 4) = p;
    }
}

// Final layer: fp32 out in TRUE feature order (un-permute: phi=4h+q -> f=h+16q),
// isi scale, no ReLU. Half-wave per node, 2 edges per load.
__global__ __launch_bounds__(256) void gather64(
    const unsigned short* __restrict__ msg, const int* __restrict__ row_ptr,
    const int* __restrict__ col, const float* __restrict__ isi,
    float* __restrict__ out, int N) {
    const int w = (blockIdx.x * 256 + threadIdx.x) >> 6;
    const int lane = threadIdx.x & 63;
    const int node = w * 2 + (lane >> 5);
    if (node >= N) return;
    const int es = (lane >> 4) & 1;  // edge slot within half-wave
    const int h = lane & 15;         // uint2 index within 128B row
    const int start = row_ptr[node], end = row_ptr[node + 1];
    const uint2* m64 = (const uint2*)msg;  // row stride 16 uint2

    float a0 = 0.f, a1 = 0.f, a2 = 0.f, a3 = 0.f;
    int e = start;
    const int efull = start + ((end - start) & ~7);
    for (; e < efull; e += 8) {
        int c[4];
        uint2 v[4];
#pragma unroll
        for (int jj = 0; jj < 4; ++jj) c[jj] = col[e + 2 * jj + es];
#pragma unroll
        for (int jj = 0; jj < 4; ++jj) v[jj] = m64[(size_t)c[jj] * 16 + h];
#pragma unroll
        for (int jj = 0; jj < 4; ++jj) {
            a0 += bf_lo(v[jj].x); a1 += bf_hi(v[jj].x);
            a2 += bf_lo(v[jj].y); a3 += bf_hi(v[jj].y);
        }
    }
    const int rem = end - e;
    if (rem > 0) {
        int c[4];
        uint2 v[4];
#pragma unroll
        for (int jj = 0; jj < 4; ++jj) c[jj] = col[e + min(2 * jj + es, rem - 1)];
#pragma unroll
        for (int jj = 0; jj < 4; ++jj) v[jj] = m64[(size_t)c[jj] * 16 + h];
#pragma unroll
        for (int jj = 0; jj < 4; ++jj) {
            if (2 * jj + es < rem) {
                a0 += bf_lo(v[jj].x); a1 += bf_hi(v[jj].x);
                a2 += bf_lo(v[jj].y); a3 += bf_hi(v[jj].y);
            }
        }
    }
    a0 += __shfl_xor(a0, 16); a1 += __shfl_xor(a1, 16);
    a2 += __shfl_xor(a2, 16); a3 += __shfl_xor(a3, 16);
    if (es == 0) {
        const float sc = isi[node];
        float* ob = out + (size_t)node * 64;
        ob[h] = a0 * sc;        // phi=4h   -> f = h
        ob[h + 16] = a1 * sc;   // phi=4h+1 -> f = h+16
        ob[h + 32] = a2 * sc;   // phi=4h+2 -> f = h+32
        ob[h + 48] = a3 * sc;   // phi=4h+3 -> f = h+48
    }
}

// ---------------- launch ----------------

extern "C" void kernel_launch(void* const* d_in, const int* in_sizes, int n_in,
                              void* d_out, int out_size, void* d_ws, size_t ws_size,
                              hipStream_t stream) {
    const float* features = (const float*)d_in[0];
    const float* W1 = (const float*)d_in[1];
    const float* W2 = (const float*)d_in[2];
    const float* W3 = (const float*)d_in[3];
    const int* src = (const int*)d_in[4];
    const int* dst = (const int*)d_in[5];
    float* out = (float*)d_out;

    const int N = in_sizes[0] / 128;  // 100000
    const int E = in_sizes[4];        // 1600000
    const int NB = (N + 255) >> 8;    // 391 buckets of 256 nodes

    char* ws = (char*)d_ws;
    unsigned short* A = (unsigned short*)ws;      ws += (size_t)N * 128 * 2;   // bf16 hidden
    unsigned short* Y = (unsigned short*)ws;      ws += (size_t)N * 128 * 2;   // bf16 messages
    int* row_ptr = (int*)ws;                      ws += (size_t)(N + 1) * 4;
    int* col = (int*)ws;                          ws += (size_t)E * 4;
    float* iso = (float*)ws;                      ws += (size_t)N * 4;
    float* isi = (float*)ws;                      ws += (size_t)N * 4;
    float* fscale = (float*)ws;                   ws += (size_t)N * 4;
    int* cur_d = (int*)ws;                        ws += MAXNB * 4;
    int* cur_s = (int*)ws;                        ws += MAXNB * 4;
    int* bbase = (int*)ws;                        ws += MAXNB * 4;
    unsigned short* Wt1h = (unsigned short*)ws;   ws += 128 * 128 * 2;
    unsigned short* Wt1l = (unsigned short*)ws;   ws += 128 * 128 * 2;
    unsigned short* Wt2h = (unsigned short*)ws;   ws += 128 * 128 * 2;
    unsigned short* Wt2l = (unsigned short*)ws;   ws += 128 * 128 * 2;
    unsigned short* Wt3h = (unsigned short*)ws;   ws += 64 * 128 * 2;
    unsigned short* Wt3l = (unsigned short*)ws;   ws += 64 * 128 * 2;

    // bucket staging aliased over A+Y head (16.4 MB; consumed by csr_outdeg
    // before gemm1/gather1 write Y/A).
    int* bpair = (int*)A;                                    // MAXNB*CAP ints
    int* bsrc = (int*)((char*)A + (size_t)MAXNB * CAP * 4);  // MAXNB*CAP ints

    wpack_all<<<160, 256, 0, stream>>>(W1, W2, W3, Wt1h, Wt1l, Wt2h, Wt2l, Wt3h, Wt3l);
    hipMemsetAsync(cur_d, 0, 2 * MAXNB * sizeof(int), stream);  // cur_d + cur_s
    const int gBS = (E + 4095) / 4096;  // 512 thr x 8 edges
    bucket_scatter<<<gBS, 512, 0, stream>>>(src, dst, cur_d, cur_s, bpair, bsrc, E, NB);
    bucket_scan<<<1, 512, 0, stream>>>(cur_d, bbase, NB);
    csr_outdeg<<<NB, 256, 0, stream>>>(bpair, bsrc, cur_d, cur_s, bbase, row_ptr,
                                       col, isi, iso, fscale, N, NB);

    const int gG = (N + 127) / 128;
    const int ga128 = (N * 64 + 255) / 256;
    const int ga64 = ((N / 2 + 1) * 64 + 255) / 256;

    // layer 1
    gemm_mfma<128><<<gG, 256, 0, stream>>>(features, Wt1h, Wt1l, iso, Y, N);
    gather128_bf16<<<ga128, 256, 0, stream>>>(Y, row_ptr, col, fscale, A, N);
    // layer 2
    gemm_bf16A<128><<<gG, 256, 0, stream>>>(A, Wt2h, Wt2l, Y, N);
    gather128_bf16<<<ga128, 256, 0, stream>>>(Y, row_ptr, col, fscale, A, N);
    // layer 3
    gemm_bf16A<64><<<gG, 256, 0, stream>>>(A, Wt3h, Wt3l, Y, N);
    gather64<<<ga64, 256, 0, stream>>>(Y, row_ptr, col, isi, out, N);
}